// Round 1
// baseline (320.320 us; speedup 1.0000x reference)
//
#include <hip/hip_runtime.h>
#include <math.h>

#define NRAY2 4096
#define NSAMP 64
#define KG 64
#define PHD 192
constexpr float STEP = 1.0f / 63.0f;

struct Mats { float crd[16]; float drv[16]; };

// ---------------- host-side constant matrices (replicates numpy fp64 math) ---
static void mat_mul4(const double* A, const double* B, double* C) {
    for (int i = 0; i < 4; ++i)
        for (int j = 0; j < 4; ++j) {
            double s = 0.0;
            for (int k = 0; k < 4; ++k) s += A[i*4+k] * B[k*4+j];
            C[i*4+j] = s;
        }
}

static void build_mats(Mats& M) {
    const double tx = 0.1, ty = 0.05, tz = 0.02;
    const double cx = 0.5, cy = 0.5, cz = 0.5;
    auto ry = [](double t, double* m) {
        double c = cos(t), s = sin(t);
        double v[16] = {1,0,0,0, 0,c,-s,0, 0,s,c,0, 0,0,0,1};
        for (int i = 0; i < 16; ++i) m[i] = v[i];
    };
    auto rx = [](double t, double* m) {
        double c = cos(t), s = sin(t);
        double v[16] = {c,0,-s,0, 0,1,0,0, s,0,c,0, 0,0,0,1};
        for (int i = 0; i < 16; ++i) m[i] = v[i];
    };
    auto rz = [](double t, double* m) {
        double c = cos(t), s = sin(t);
        double v[16] = {c,-s,0,0, s,c,0,0, 0,0,1,0, 0,0,0,1};
        for (int i = 0; i < 16; ++i) m[i] = v[i];
    };
    double RY[16], RY_[16], RX[16], RX_[16], RZ[16], RZ_[16];
    ry(-ty, RY); ry(ty, RY_);
    rx(tx, RX);  rx(-tx, RX_);
    rz(-tz, RZ); rz(tz, RZ_);
    double S1[16] = {1,0,0,0, 0,1,0,0, 0,0,1,0, -cx,-cy,-cz,1};
    double S2[16] = {1,0,0,0, 0,1,0,0, 0,0,1,0,  cx, cy, cz,1};
    double t1[16], t2[16], t3[16], Mc[16], Md[16];
    // M_crd = S1 @ RZ @ RY @ RX @ S2  (left-to-right)
    mat_mul4(S1, RZ, t1);
    mat_mul4(t1, RY, t2);
    mat_mul4(t2, RX, t3);
    mat_mul4(t3, S2, Mc);
    // M_drv = RX_ @ RY_ @ RZ_
    mat_mul4(RX_, RY_, t1);
    mat_mul4(t1, RZ_, Md);
    for (int i = 0; i < 16; ++i) { M.crd[i] = (float)Mc[i]; M.drv[i] = (float)Md[i]; }
}

// ---------------- kernel 1: ray tracing -------------------------------------
// 32 lanes per ray (27 active neighbors), 2 rays per wave, 8 rays per block.
__global__ __launch_bounds__(256) void ray_trace_kernel(
    const float* __restrict__ RI,       // (64^3, 2) interleaved [A, sig]
    const float* __restrict__ RayInit,  // (4096, 5)
    float* __restrict__ meshX,          // (4096, 64)  stores 2X-1
    float* __restrict__ meshY,          // (4096, 64)  stores 2Y-1
    Mats M)
{
    const int tid  = threadIdx.x;
    const int nb   = tid & 31;                    // neighbor lane within half-wave
    const int ray  = blockIdx.x * 8 + (tid >> 5);
    const bool act = nb < 27;

    float xr = 0.f, yr = 0.f, zr = 0.f;
    if (act) {
        int a0 = nb / 9, a1 = (nb / 3) % 3, a2 = nb % 3;
        xr = (float)(a1 - 1);   // XR varies along meshgrid axis 1
        yr = (float)(a0 - 1);   // YR along axis 0
        zr = (float)(a2 - 1);   // ZR along axis 2
    }

    float X  = RayInit[ray*5 + 0];
    float dX = RayInit[ray*5 + 1];
    float Y  = RayInit[ray*5 + 2];
    float dY = RayInit[ray*5 + 3];
    float z  = RayInit[ray*5 + 4];

    if (nb == 0) meshX[ray*64 + 0] = X*2.0f - 1.0f;
    if (nb == 1) meshY[ray*64 + 0] = Y*2.0f - 1.0f;

    for (int s = 1; s < NSAMP; ++s) {
        // t = [Y, X, z, 1] @ M_crd ; indexdist args: x=t[1], y=t[0], z=t[2]
        float x  = Y*M.crd[0*4+1] + X*M.crd[1*4+1] + z*M.crd[2*4+1] + M.crd[3*4+1];
        float y  = Y*M.crd[0*4+0] + X*M.crd[1*4+0] + z*M.crd[2*4+0] + M.crd[3*4+0];
        float zz = Y*M.crd[0*4+2] + X*M.crd[1*4+2] + z*M.crd[2*4+2] + M.crd[3*4+2];

        float ni = 0.f, nuA = 0.f, sx = 0.f, sy = 0.f, sz = 0.f,
              sdx = 0.f, sdy = 0.f, sdz = 0.f;
        if (act) {
            float Xn = fminf(fmaxf(rintf(x  * 64.0f) + xr, 0.0f), 63.0f);
            float Yn = fminf(fmaxf(rintf(y  * 64.0f) + yr, 0.0f), 63.0f);
            float Zn = fminf(fmaxf(rintf(zz * 64.0f) + zr, 0.0f), 63.0f);
            int lin = ((int)Yn << 12) + ((int)Xn << 6) + (int)Zn;
            float2 ri = *(const float2*)(RI + 2*lin);   // A, sig
            float dx = Xn * (1.0f/63.0f) - x;
            float dy = Yn * (1.0f/63.0f) - y;
            float dz = Zn * (1.0f/63.0f) - zz;
            float inv_s2 = 1.0f / (ri.y * ri.y);
            float e = expf(-(dx*dx + dy*dy + dz*dz) * 0.5f * inv_s2) + 2e-7f;
            float gdx = dx * inv_s2, gdy = dy * inv_s2, gdz = dz * inv_s2;
            float nu = e * ri.x;
            ni = e; nuA = nu;
            sx  = nu * gdx; sy  = nu * gdy; sz  = nu * gdz;
            sdx = e  * gdx; sdy = e  * gdy; sdz = e  * gdz;
        }

        // butterfly reduction across the 32-lane half-wave
        #pragma unroll
        for (int m = 16; m >= 1; m >>= 1) {
            ni  += __shfl_xor(ni,  m, 32);
            nuA += __shfl_xor(nuA, m, 32);
            sx  += __shfl_xor(sx,  m, 32);
            sy  += __shfl_xor(sy,  m, 32);
            sz  += __shfl_xor(sz,  m, 32);
            sdx += __shfl_xor(sdx, m, 32);
            sdy += __shfl_xor(sdy, m, 32);
            sdz += __shfl_xor(sdz, m, 32);
        }

        float n_      = nuA / ni;
        float inv_n2  = 1.0f / (ni * ni);
        float gx_ = (ni*sx - nuA*sdx) * inv_n2;   // dndx_
        float gy_ = (ni*sy - nuA*sdy) * inv_n2;   // dndy_
        float gz_ = (ni*sz - nuA*sdz) * inv_n2;   // dndz_

        // d = [gy_, gx_, gz_, 1] @ M_drv ; dndx=d[1], dndy=d[0], dndz=d[2]
        float dndx = gy_*M.drv[0*4+1] + gx_*M.drv[1*4+1] + gz_*M.drv[2*4+1] + M.drv[3*4+1];
        float dndy = gy_*M.drv[0*4+0] + gx_*M.drv[1*4+0] + gz_*M.drv[2*4+0] + M.drv[3*4+0];
        float dndz = gy_*M.drv[0*4+2] + gx_*M.drv[1*4+2] + gz_*M.drv[2*4+2] + M.drv[3*4+2];

        float dX2 = (dndx - dndz*dX) * (1.0f + dX*dX) / n_;
        float dY2 = (dndy - dndz*dY) * (1.0f + dY*dY) / n_;

        X  += dX  * STEP;   // uses old dX (dX1)
        dX += dX2 * STEP;
        Y  += dY  * STEP;
        dY += dY2 * STEP;
        z  += STEP;

        if (nb == 0) meshX[ray*64 + s] = X*2.0f - 1.0f;
        if (nb == 1) meshY[ray*64 + s] = Y*2.0f - 1.0f;
    }
}

// ---------------- kernel 2: fused resize + grid sample ----------------------
// iz collapses to exactly c (mesh[2] is linear in s, identical per ray), so
// fz = 0 and only the dz=0 plane contributes -> 4 phantom gathers per voxel.
__global__ __launch_bounds__(192) void sample_kernel(
    const float* __restrict__ vol,     // 192^3
    const float* __restrict__ meshX,   // (64,64,64) flat [i][j][s]
    const float* __restrict__ meshY,
    float* __restrict__ out)           // 192^3, [a][b][c]
{
    const int c = threadIdx.x;
    const int b = blockIdx.x;
    const int a = blockIdx.y;

    const float scale = 63.0f / 191.0f;
    float pa = a * scale; int i0 = min((int)floorf(pa), 62); float wa = pa - (float)i0;
    float pb = b * scale; int j0 = min((int)floorf(pb), 62); float wb = pb - (float)j0;
    float pc = c * scale; int s0 = min((int)floorf(pc), 62); float wc = pc - (float)s0;

    const int r00 = (i0*64 + j0)     * 64 + s0;
    const int r01 = (i0*64 + j0 + 1) * 64 + s0;
    const int r10 = ((i0+1)*64 + j0)     * 64 + s0;
    const int r11 = ((i0+1)*64 + j0 + 1) * 64 + s0;

    float wc0 = 1.0f - wc;
    float x00 = meshX[r00]*wc0 + meshX[r00+1]*wc;
    float x01 = meshX[r01]*wc0 + meshX[r01+1]*wc;
    float x10 = meshX[r10]*wc0 + meshX[r10+1]*wc;
    float x11 = meshX[r11]*wc0 + meshX[r11+1]*wc;
    float y00 = meshY[r00]*wc0 + meshY[r00+1]*wc;
    float y01 = meshY[r01]*wc0 + meshY[r01+1]*wc;
    float y10 = meshY[r10]*wc0 + meshY[r10+1]*wc;
    float y11 = meshY[r11]*wc0 + meshY[r11+1]*wc;

    float wb0 = 1.0f - wb, wa0 = 1.0f - wa;
    float gx = (x00*wb0 + x01*wb)*wa0 + (x10*wb0 + x11*wb)*wa;
    float gy = (y00*wb0 + y01*wb)*wa0 + (y10*wb0 + y11*wb)*wa;

    float ix = (gx + 1.0f) * 0.5f * 191.0f;
    float iy = (gy + 1.0f) * 0.5f * 191.0f;
    float x0f = floorf(ix); float fx = ix - x0f;
    float y0f = floorf(iy); float fy = iy - y0f;

    const float* plane = vol + c * (PHD*PHD);
    float acc = 0.0f;
    #pragma unroll
    for (int dyy = 0; dyy < 2; ++dyy) {
        #pragma unroll
        for (int dxx = 0; dxx < 2; ++dxx) {
            float xi = x0f + (float)dxx;
            float yi = y0f + (float)dyy;
            bool inb = (xi >= 0.0f) && (xi <= 191.0f) && (yi >= 0.0f) && (yi <= 191.0f);
            if (inb) {
                int xc = (int)xi, yc = (int)yi;
                float w = (dxx ? fx : 1.0f - fx) * (dyy ? fy : 1.0f - fy);
                acc += w * plane[yc*PHD + xc];
            }
        }
    }
    out[(a*PHD + b)*PHD + c] = acc;
}

// ---------------- launch -----------------------------------------------------
extern "C" void kernel_launch(void* const* d_in, const int* in_sizes, int n_in,
                              void* d_out, int out_size, void* d_ws, size_t ws_size,
                              hipStream_t stream)
{
    const float* Phantom = (const float*)d_in[0];   // 192^3
    const float* RI      = (const float*)d_in[1];   // (64^3, 2)
    const float* RayInit = (const float*)d_in[2];   // (4096, 5)
    float* out = (float*)d_out;

    float* meshX = (float*)d_ws;                    // 64^3 floats
    float* meshY = meshX + NRAY2 * NSAMP;           // 64^3 floats

    Mats M;
    build_mats(M);

    ray_trace_kernel<<<NRAY2/8, 256, 0, stream>>>(RI, RayInit, meshX, meshY, M);
    sample_kernel<<<dim3(PHD, PHD), PHD, 0, stream>>>(Phantom, meshX, meshY, out);
}

// Round 2
// 279.343 us; speedup vs baseline: 1.1467x; 1.1467x over previous
//
#include <hip/hip_runtime.h>
#include <math.h>

#define NRAY2 4096
#define NSAMP 64
#define KG 64
#define PHD 192
constexpr float STEP = 1.0f / 63.0f;

struct Mats { float crd[16]; float drv[16]; };

// ---------------- host-side constant matrices (replicates numpy fp64 math) ---
static void mat_mul4(const double* A, const double* B, double* C) {
    for (int i = 0; i < 4; ++i)
        for (int j = 0; j < 4; ++j) {
            double s = 0.0;
            for (int k = 0; k < 4; ++k) s += A[i*4+k] * B[k*4+j];
            C[i*4+j] = s;
        }
}

static void build_mats(Mats& M) {
    const double tx = 0.1, ty = 0.05, tz = 0.02;
    const double cx = 0.5, cy = 0.5, cz = 0.5;
    auto ry = [](double t, double* m) {
        double c = cos(t), s = sin(t);
        double v[16] = {1,0,0,0, 0,c,-s,0, 0,s,c,0, 0,0,0,1};
        for (int i = 0; i < 16; ++i) m[i] = v[i];
    };
    auto rx = [](double t, double* m) {
        double c = cos(t), s = sin(t);
        double v[16] = {c,0,-s,0, 0,1,0,0, s,0,c,0, 0,0,0,1};
        for (int i = 0; i < 16; ++i) m[i] = v[i];
    };
    auto rz = [](double t, double* m) {
        double c = cos(t), s = sin(t);
        double v[16] = {c,-s,0,0, s,c,0,0, 0,0,1,0, 0,0,0,1};
        for (int i = 0; i < 16; ++i) m[i] = v[i];
    };
    double RY[16], RY_[16], RX[16], RX_[16], RZ[16], RZ_[16];
    ry(-ty, RY); ry(ty, RY_);
    rx(tx, RX);  rx(-tx, RX_);
    rz(-tz, RZ); rz(tz, RZ_);
    double S1[16] = {1,0,0,0, 0,1,0,0, 0,0,1,0, -cx,-cy,-cz,1};
    double S2[16] = {1,0,0,0, 0,1,0,0, 0,0,1,0,  cx, cy, cz,1};
    double t1[16], t2[16], t3[16], Mc[16], Md[16];
    mat_mul4(S1, RZ, t1);
    mat_mul4(t1, RY, t2);
    mat_mul4(t2, RX, t3);
    mat_mul4(t3, S2, Mc);
    mat_mul4(RX_, RY_, t1);
    mat_mul4(t1, RZ_, Md);
    for (int i = 0; i < 16; ++i) { M.crd[i] = (float)Mc[i]; M.drv[i] = (float)Md[i]; }
}

// ---------------- kernel 1: ray tracing -------------------------------------
// 32 lanes per ray (27 active neighbors), 2 rays per wave, 8 rays per block.
// Divides -> v_rcp_f32, expf -> __expf (v_exp_f32): shortens the 63-step
// serial dependence chain (we are latency-bound at 8 waves/CU).
__global__ __launch_bounds__(256) void ray_trace_kernel(
    const float* __restrict__ RI,       // (64^3, 2) interleaved [A, sig]
    const float* __restrict__ RayInit,  // (4096, 5)
    float* __restrict__ meshX,          // (4096, 64)  stores 2X-1
    float* __restrict__ meshY,          // (4096, 64)  stores 2Y-1
    Mats M)
{
    const int tid  = threadIdx.x;
    const int nb   = tid & 31;
    const int ray  = blockIdx.x * 8 + (tid >> 5);
    const bool act = nb < 27;

    float xr = 0.f, yr = 0.f, zr = 0.f;
    if (act) {
        int a0 = nb / 9, a1 = (nb / 3) % 3, a2 = nb % 3;
        xr = (float)(a1 - 1);
        yr = (float)(a0 - 1);
        zr = (float)(a2 - 1);
    }

    float X  = RayInit[ray*5 + 0];
    float dX = RayInit[ray*5 + 1];
    float Y  = RayInit[ray*5 + 2];
    float dY = RayInit[ray*5 + 3];
    float z  = RayInit[ray*5 + 4];

    if (nb == 0) meshX[ray*64 + 0] = X*2.0f - 1.0f;
    if (nb == 1) meshY[ray*64 + 0] = Y*2.0f - 1.0f;

    for (int s = 1; s < NSAMP; ++s) {
        float x  = Y*M.crd[0*4+1] + X*M.crd[1*4+1] + z*M.crd[2*4+1] + M.crd[3*4+1];
        float y  = Y*M.crd[0*4+0] + X*M.crd[1*4+0] + z*M.crd[2*4+0] + M.crd[3*4+0];
        float zz = Y*M.crd[0*4+2] + X*M.crd[1*4+2] + z*M.crd[2*4+2] + M.crd[3*4+2];

        float ni = 0.f, nuA = 0.f, sx = 0.f, sy = 0.f, sz = 0.f,
              sdx = 0.f, sdy = 0.f, sdz = 0.f;
        if (act) {
            float Xn = fminf(fmaxf(rintf(x  * 64.0f) + xr, 0.0f), 63.0f);
            float Yn = fminf(fmaxf(rintf(y  * 64.0f) + yr, 0.0f), 63.0f);
            float Zn = fminf(fmaxf(rintf(zz * 64.0f) + zr, 0.0f), 63.0f);
            int lin = ((int)Yn << 12) + ((int)Xn << 6) + (int)Zn;
            float2 ri = *(const float2*)(RI + 2*lin);   // A, sig
            float dx = Xn * (1.0f/63.0f) - x;
            float dy = Yn * (1.0f/63.0f) - y;
            float dz = Zn * (1.0f/63.0f) - zz;
            float inv_s2 = __builtin_amdgcn_rcpf(ri.y * ri.y);
            float e = __expf(-(dx*dx + dy*dy + dz*dz) * 0.5f * inv_s2) + 2e-7f;
            float gdx = dx * inv_s2, gdy = dy * inv_s2, gdz = dz * inv_s2;
            float nu = e * ri.x;
            ni = e; nuA = nu;
            sx  = nu * gdx; sy  = nu * gdy; sz  = nu * gdz;
            sdx = e  * gdx; sdy = e  * gdy; sdz = e  * gdz;
        }

        #pragma unroll
        for (int m = 16; m >= 1; m >>= 1) {
            ni  += __shfl_xor(ni,  m, 32);
            nuA += __shfl_xor(nuA, m, 32);
            sx  += __shfl_xor(sx,  m, 32);
            sy  += __shfl_xor(sy,  m, 32);
            sz  += __shfl_xor(sz,  m, 32);
            sdx += __shfl_xor(sdx, m, 32);
            sdy += __shfl_xor(sdy, m, 32);
            sdz += __shfl_xor(sdz, m, 32);
        }

        float r    = __builtin_amdgcn_rcpf(ni);
        float n_   = nuA * r;
        float rn   = __builtin_amdgcn_rcpf(n_);
        float in2  = r * r;
        float gx_ = (ni*sx - nuA*sdx) * in2;
        float gy_ = (ni*sy - nuA*sdy) * in2;
        float gz_ = (ni*sz - nuA*sdz) * in2;

        float dndx = gy_*M.drv[0*4+1] + gx_*M.drv[1*4+1] + gz_*M.drv[2*4+1] + M.drv[3*4+1];
        float dndy = gy_*M.drv[0*4+0] + gx_*M.drv[1*4+0] + gz_*M.drv[2*4+0] + M.drv[3*4+0];
        float dndz = gy_*M.drv[0*4+2] + gx_*M.drv[1*4+2] + gz_*M.drv[2*4+2] + M.drv[3*4+2];

        float dX2 = (dndx - dndz*dX) * (1.0f + dX*dX) * rn;
        float dY2 = (dndy - dndz*dY) * (1.0f + dY*dY) * rn;

        X  += dX  * STEP;
        dX += dX2 * STEP;
        Y  += dY  * STEP;
        dY += dY2 * STEP;
        z  += STEP;

        if (nb == 0) meshX[ray*64 + s] = X*2.0f - 1.0f;
        if (nb == 1) meshY[ray*64 + s] = Y*2.0f - 1.0f;
    }
}

// ---------------- kernel 2: fused resize + grid sample ----------------------
// One block per output c-plane (192 blocks x 1024 threads). The phantom plane
// for this c lives entirely in LDS (147,456 B; gfx950 LDS = 160 KiB/CU), so
// the 4 random bilinear gathers per voxel are ds_read_b32 instead of
// line-amplified HBM/L2 traffic. iz collapses to exactly c (fz = 0).
__global__ __launch_bounds__(1024) void sample_kernel(
    const float* __restrict__ vol,     // 192^3
    const float* __restrict__ meshX,   // (64,64,64) flat [i][j][s]
    const float* __restrict__ meshY,
    float* __restrict__ out)           // 192^3, [a][b][c]
{
    __shared__ float plane[PHD*PHD];   // 147,456 B
    __shared__ float wTab[PHD];
    __shared__ int   iTab[PHD];

    const int tid = threadIdx.x;
    const int blk = blockIdx.x;
    // XCD-locality swizzle: consecutive c on the same XCD so the 16-c output
    // lines get merged in one L2. (dispatch round-robins blocks over 8 XCDs)
    const int c = (blk >> 3) + 24 * (blk & 7);

    if (tid < PHD) {
        float p = tid * (63.0f / 191.0f);
        int i0 = min((int)p, 62);
        iTab[tid] = i0;
        wTab[tid] = p - (float)i0;
    }

    const float4* src = (const float4*)(vol + c * (PHD*PHD));
    float4* dst = (float4*)plane;
    #pragma unroll
    for (int k = 0; k < (PHD*PHD/4)/1024; ++k)
        dst[tid + k*1024] = src[tid + k*1024];
    __syncthreads();

    // block-uniform s interpolation
    float ps = c * (63.0f / 191.0f);
    int s0 = min((int)ps, 62);
    float wc = ps - (float)s0, wc0 = 1.0f - wc;

    int a = tid / PHD, b = tid % PHD;
    #pragma unroll 1
    for (int k = 0; k < (PHD*PHD)/1024; ++k) {
        int i0 = iTab[a]; float wa = wTab[a];
        int j0 = iTab[b]; float wb = wTab[b];

        const int r00 = (i0*64 + j0)     * 64 + s0;
        const int r01 = (i0*64 + j0 + 1) * 64 + s0;
        const int r10 = ((i0+1)*64 + j0)     * 64 + s0;
        const int r11 = ((i0+1)*64 + j0 + 1) * 64 + s0;

        float x00 = meshX[r00]*wc0 + meshX[r00+1]*wc;
        float x01 = meshX[r01]*wc0 + meshX[r01+1]*wc;
        float x10 = meshX[r10]*wc0 + meshX[r10+1]*wc;
        float x11 = meshX[r11]*wc0 + meshX[r11+1]*wc;
        float y00 = meshY[r00]*wc0 + meshY[r00+1]*wc;
        float y01 = meshY[r01]*wc0 + meshY[r01+1]*wc;
        float y10 = meshY[r10]*wc0 + meshY[r10+1]*wc;
        float y11 = meshY[r11]*wc0 + meshY[r11+1]*wc;

        float wb0 = 1.0f - wb, wa0 = 1.0f - wa;
        float gx = (x00*wb0 + x01*wb)*wa0 + (x10*wb0 + x11*wb)*wa;
        float gy = (y00*wb0 + y01*wb)*wa0 + (y10*wb0 + y11*wb)*wa;

        float ix = (gx + 1.0f) * 0.5f * 191.0f;
        float iy = (gy + 1.0f) * 0.5f * 191.0f;
        float x0f = floorf(ix); float fx = ix - x0f;
        float y0f = floorf(iy); float fy = iy - y0f;

        float acc = 0.0f;
        #pragma unroll
        for (int dyy = 0; dyy < 2; ++dyy) {
            #pragma unroll
            for (int dxx = 0; dxx < 2; ++dxx) {
                float xi = x0f + (float)dxx;
                float yi = y0f + (float)dyy;
                bool inb = (xi >= 0.0f) && (xi <= 191.0f) &&
                           (yi >= 0.0f) && (yi <= 191.0f);
                int xc = min(max((int)xi, 0), PHD - 1);
                int yc = min(max((int)yi, 0), PHD - 1);
                float w = (dxx ? fx : 1.0f - fx) * (dyy ? fy : 1.0f - fy);
                float val = plane[yc*PHD + xc];
                acc += inb ? w * val : 0.0f;
            }
        }
        out[(a*PHD + b)*PHD + c] = acc;

        // advance linear index by 1024: 1024 = 5*192 + 64
        a += 5; b += 64;
        if (b >= PHD) { b -= PHD; a += 1; }
    }
}

// ---------------- launch -----------------------------------------------------
extern "C" void kernel_launch(void* const* d_in, const int* in_sizes, int n_in,
                              void* d_out, int out_size, void* d_ws, size_t ws_size,
                              hipStream_t stream)
{
    const float* Phantom = (const float*)d_in[0];   // 192^3
    const float* RI      = (const float*)d_in[1];   // (64^3, 2)
    const float* RayInit = (const float*)d_in[2];   // (4096, 5)
    float* out = (float*)d_out;

    float* meshX = (float*)d_ws;                    // 64^3 floats
    float* meshY = meshX + NRAY2 * NSAMP;           // 64^3 floats

    Mats M;
    build_mats(M);

    ray_trace_kernel<<<NRAY2/8, 256, 0, stream>>>(RI, RayInit, meshX, meshY, M);
    sample_kernel<<<PHD, 1024, 0, stream>>>(Phantom, meshX, meshY, out);
}

// Round 3
// 163.802 us; speedup vs baseline: 1.9555x; 1.7054x over previous
//
#include <hip/hip_runtime.h>
#include <math.h>

#define NRAY2 4096
#define NSAMP 64
#define PHD 192
constexpr float STEP = 1.0f / 63.0f;

struct Mats { float crd[16]; float drv[16]; };

// ---------------- host-side constant matrices (replicates numpy fp64 math) ---
static void mat_mul4(const double* A, const double* B, double* C) {
    for (int i = 0; i < 4; ++i)
        for (int j = 0; j < 4; ++j) {
            double s = 0.0;
            for (int k = 0; k < 4; ++k) s += A[i*4+k] * B[k*4+j];
            C[i*4+j] = s;
        }
}

static void build_mats(Mats& M) {
    const double tx = 0.1, ty = 0.05, tz = 0.02;
    const double cx = 0.5, cy = 0.5, cz = 0.5;
    auto ry = [](double t, double* m) {
        double c = cos(t), s = sin(t);
        double v[16] = {1,0,0,0, 0,c,-s,0, 0,s,c,0, 0,0,0,1};
        for (int i = 0; i < 16; ++i) m[i] = v[i];
    };
    auto rx = [](double t, double* m) {
        double c = cos(t), s = sin(t);
        double v[16] = {c,0,-s,0, 0,1,0,0, s,0,c,0, 0,0,0,1};
        for (int i = 0; i < 16; ++i) m[i] = v[i];
    };
    auto rz = [](double t, double* m) {
        double c = cos(t), s = sin(t);
        double v[16] = {c,-s,0,0, s,c,0,0, 0,0,1,0, 0,0,0,1};
        for (int i = 0; i < 16; ++i) m[i] = v[i];
    };
    double RY[16], RY_[16], RX[16], RX_[16], RZ[16], RZ_[16];
    ry(-ty, RY); ry(ty, RY_);
    rx(tx, RX);  rx(-tx, RX_);
    rz(-tz, RZ); rz(tz, RZ_);
    double S1[16] = {1,0,0,0, 0,1,0,0, 0,0,1,0, -cx,-cy,-cz,1};
    double S2[16] = {1,0,0,0, 0,1,0,0, 0,0,1,0,  cx, cy, cz,1};
    double t1[16], t2[16], t3[16], Mc[16], Md[16];
    mat_mul4(S1, RZ, t1);
    mat_mul4(t1, RY, t2);
    mat_mul4(t2, RX, t3);
    mat_mul4(t3, S2, Mc);
    mat_mul4(RX_, RY_, t1);
    mat_mul4(t1, RZ_, Md);
    for (int i = 0; i < 16; ++i) { M.crd[i] = (float)Mc[i]; M.drv[i] = (float)Md[i]; }
}

// 32-lane sum, all lanes get result: 4x DPP row_ror (VALU pipe, short latency)
// then one ds_swizzle xor-16 across the two 16-rows.
__device__ __forceinline__ float red32(float x) {
    int t;
    t = __builtin_amdgcn_update_dpp(0, __float_as_int(x), 0x121, 0xF, 0xF, true); // row_ror:1
    x += __int_as_float(t);
    t = __builtin_amdgcn_update_dpp(0, __float_as_int(x), 0x122, 0xF, 0xF, true); // row_ror:2
    x += __int_as_float(t);
    t = __builtin_amdgcn_update_dpp(0, __float_as_int(x), 0x124, 0xF, 0xF, true); // row_ror:4
    x += __int_as_float(t);
    t = __builtin_amdgcn_update_dpp(0, __float_as_int(x), 0x128, 0xF, 0xF, true); // row_ror:8
    x += __int_as_float(t);
    t = __builtin_amdgcn_ds_swizzle(__float_as_int(x), 0x401F);                   // lane ^= 16
    x += __int_as_float(t);
    return x;
}

// ---------------- kernel 1: ray tracing -------------------------------------
// 32 lanes per ray (27 active neighbors), 2 rays/wave. One-step-ahead RI
// prefetch: eval position for step s+1 needs only pre-reduction state, so its
// gather issues at the top of step s and has the whole body in flight.
// Mesh written TRANSPOSED: meshXT[s*4096 + ray] (coalesced slice loads later).
__global__ __launch_bounds__(256) void ray_trace_kernel(
    const float* __restrict__ RI,       // (64^3, 2) interleaved [A, sig]
    const float* __restrict__ RayInit,  // (4096, 5)
    float* __restrict__ meshXT,         // (64, 4096)  stores 2X-1
    float* __restrict__ meshYT,         // (64, 4096)  stores 2Y-1
    Mats M)
{
    const int tid = threadIdx.x;
    const int nb  = tid & 31;
    const int ray = blockIdx.x * 8 + (tid >> 5);
    const bool act = nb < 27;

    float xr = 0.f, yr = 0.f, zr = 0.f;
    if (act) {
        int a0 = nb / 9, a1 = (nb / 3) % 3, a2 = nb % 3;
        xr = (float)(a1 - 1);
        yr = (float)(a0 - 1);
        zr = (float)(a2 - 1);
    }

    float X  = RayInit[ray*5 + 0];
    float dX = RayInit[ray*5 + 1];
    float Y  = RayInit[ray*5 + 2];
    float dY = RayInit[ray*5 + 3];
    float z  = RayInit[ray*5 + 4];

    if (nb == 0) meshXT[ray] = X*2.0f - 1.0f;
    if (nb == 1) meshYT[ray] = Y*2.0f - 1.0f;

    // transform + cell for an eval position; returns gather pointer
    auto prep = [&](float pX, float pY, float pz,
                    float& ox, float& oy, float& oz,
                    float& oXn, float& oYn, float& oZn) -> const float2* {
        float x  = pY*M.crd[1] + pX*M.crd[5] + pz*M.crd[9]  + M.crd[13];
        float y  = pY*M.crd[0] + pX*M.crd[4] + pz*M.crd[8]  + M.crd[12];
        float zz = pY*M.crd[2] + pX*M.crd[6] + pz*M.crd[10] + M.crd[14];
        float XnL = fminf(fmaxf(rintf(x *64.0f) + xr, 0.0f), 63.0f);
        float YnL = fminf(fmaxf(rintf(y *64.0f) + yr, 0.0f), 63.0f);
        float ZnL = fminf(fmaxf(rintf(zz*64.0f) + zr, 0.0f), 63.0f);
        int lin = ((int)YnL << 12) + ((int)XnL << 6) + (int)ZnL;
        ox = x; oy = y; oz = zz; oXn = XnL; oYn = YnL; oZn = ZnL;
        return (const float2*)RI + lin;
    };

    float cx_, cy_, cz_, Xn, Yn, Zn;
    float2 ri = *prep(X, Y, z, cx_, cy_, cz_, Xn, Yn, Zn);   // gather for eval 1

    for (int s = 1; s < NSAMP; ++s) {
        // next eval position (needs only pre-reduction state) -> issue gather NOW
        float nX = X + dX*STEP, nY = Y + dY*STEP, nz = z + STEP;
        float ncx, ncy, ncz, nXn, nYn, nZn;
        float2 ri_n = *prep(nX, nY, nz, ncx, ncy, ncz, nXn, nYn, nZn);

        // evaluate with already-fetched ri at current position
        float dx = Xn*(1.0f/63.0f) - cx_;
        float dy = Yn*(1.0f/63.0f) - cy_;
        float dz = Zn*(1.0f/63.0f) - cz_;
        float inv_s2 = __builtin_amdgcn_rcpf(ri.y * ri.y);
        float e = __expf(-(dx*dx + dy*dy + dz*dz) * 0.5f * inv_s2) + 2e-7f;
        if (!act) e = 0.0f;                       // inactive lanes contribute 0
        float gdx = dx*inv_s2, gdy = dy*inv_s2, gdz = dz*inv_s2;
        float nu  = e * ri.x;

        float ni  = red32(e);
        float nuA = red32(nu);
        float sx  = red32(nu * gdx);
        float sy  = red32(nu * gdy);
        float sz  = red32(nu * gdz);
        float sdx = red32(e  * gdx);
        float sdy = red32(e  * gdy);
        float sdz = red32(e  * gdz);

        float r   = __builtin_amdgcn_rcpf(ni);
        float rn  = ni * __builtin_amdgcn_rcpf(nuA);   // 1/n = norm/nu_s
        float in2 = r * r;
        float gx_ = (ni*sx - nuA*sdx) * in2;
        float gy_ = (ni*sy - nuA*sdy) * in2;
        float gz_ = (ni*sz - nuA*sdz) * in2;

        float dndx = gy_*M.drv[1] + gx_*M.drv[5] + gz_*M.drv[9]  + M.drv[13];
        float dndy = gy_*M.drv[0] + gx_*M.drv[4] + gz_*M.drv[8]  + M.drv[12];
        float dndz = gy_*M.drv[2] + gx_*M.drv[6] + gz_*M.drv[10] + M.drv[14];

        float dX2 = (dndx - dndz*dX) * (1.0f + dX*dX) * rn;
        float dY2 = (dndy - dndz*dY) * (1.0f + dY*dY) * rn;

        X = nX; Y = nY; z = nz;
        dX += dX2 * STEP;
        dY += dY2 * STEP;

        if (nb == 0) meshXT[s*NRAY2 + ray] = X*2.0f - 1.0f;
        if (nb == 1) meshYT[s*NRAY2 + ray] = Y*2.0f - 1.0f;

        cx_ = ncx; cy_ = ncy; cz_ = ncz;
        Xn = nXn; Yn = nYn; Zn = nZn;
        ri = ri_n;
    }
}

// ---------------- kernel 2: fused resize + grid sample ----------------------
// One block per c-plane. Phantom plane in LDS as fp16 (73.7 KB, err<=2.4e-4);
// s-interpolated mesh slice (64x64 float2, 32 KB) in LDS from the TRANSPOSED
// mesh (coalesced). Hot loop: 4 ds_read_b64 + 4 ds_read_u16, zero VMEM loads.
typedef _Float16 h16;
typedef _Float16 h16v4 __attribute__((ext_vector_type(4)));

__global__ __launch_bounds__(1024) void sample_kernel(
    const float* __restrict__ vol,      // 192^3
    const float* __restrict__ meshXT,   // (64, 4096)
    const float* __restrict__ meshYT,
    float* __restrict__ out)            // 192^3, [a][b][c]
{
    __shared__ h16    plane_h[PHD*PHD];   // 73,728 B
    __shared__ float2 slice[64*64];       // 32,768 B  (sx, sy) at fixed s
    __shared__ float  wTab[PHD];
    __shared__ int    iTab[PHD];

    const int tid = threadIdx.x;
    const int blk = blockIdx.x;
    // XCD swizzle: consecutive c (sharing 64B output lines) on the same XCD.
    const int c = (blk >> 3) + 24 * (blk & 7);

    if (tid < PHD) {
        float p = tid * (63.0f / 191.0f);
        int i0 = min((int)p, 62);
        iTab[tid] = i0;
        wTab[tid] = p - (float)i0;
    }

    // stage phantom plane c -> fp16 LDS (coalesced float4 loads)
    {
        const float4* src = (const float4*)(vol + c * (PHD*PHD));
        h16v4* dst = (h16v4*)plane_h;
        #pragma unroll
        for (int k = 0; k < (PHD*PHD/4)/1024; ++k) {
            float4 v = src[tid + k*1024];
            h16v4 hv = {(h16)v.x, (h16)v.y, (h16)v.z, (h16)v.w};
            dst[tid + k*1024] = hv;
        }
    }

    // s-interpolation weights (block-uniform) + slice build (coalesced)
    float ps = c * (63.0f / 191.0f);
    int s0 = min((int)ps, 62);
    float wc = ps - (float)s0, wc0 = 1.0f - wc;
    {
        const float* x0 = meshXT + s0*NRAY2;
        const float* x1 = meshXT + (s0+1)*NRAY2;
        const float* y0 = meshYT + s0*NRAY2;
        const float* y1 = meshYT + (s0+1)*NRAY2;
        #pragma unroll
        for (int k = 0; k < 4096/1024; ++k) {
            int t = tid + k*1024;
            slice[t] = make_float2(x0[t]*wc0 + x1[t]*wc,
                                   y0[t]*wc0 + y1[t]*wc);
        }
    }
    __syncthreads();

    int a = tid / PHD, b = tid % PHD;
    #pragma unroll 2
    for (int k = 0; k < (PHD*PHD)/1024; ++k) {
        int i0 = iTab[a]; float wa = wTab[a];
        int j0 = iTab[b]; float wb = wTab[b];

        float2 s00 = slice[i0*64 + j0];
        float2 s01 = slice[i0*64 + j0 + 1];
        float2 s10 = slice[(i0+1)*64 + j0];
        float2 s11 = slice[(i0+1)*64 + j0 + 1];

        float wb0 = 1.0f - wb, wa0 = 1.0f - wa;
        float gx = (s00.x*wb0 + s01.x*wb)*wa0 + (s10.x*wb0 + s11.x*wb)*wa;
        float gy = (s00.y*wb0 + s01.y*wb)*wa0 + (s10.y*wb0 + s11.y*wb)*wa;

        float ix = (gx + 1.0f) * 0.5f * 191.0f;
        float iy = (gy + 1.0f) * 0.5f * 191.0f;
        float x0f = floorf(ix); float fx = ix - x0f;
        float y0f = floorf(iy); float fy = iy - y0f;

        float acc = 0.0f;
        #pragma unroll
        for (int dyy = 0; dyy < 2; ++dyy) {
            #pragma unroll
            for (int dxx = 0; dxx < 2; ++dxx) {
                float xi = x0f + (float)dxx;
                float yi = y0f + (float)dyy;
                bool inb = (xi >= 0.0f) && (xi <= 191.0f) &&
                           (yi >= 0.0f) && (yi <= 191.0f);
                int xc = min(max((int)xi, 0), PHD - 1);
                int yc = min(max((int)yi, 0), PHD - 1);
                float w = (dxx ? fx : 1.0f - fx) * (dyy ? fy : 1.0f - fy);
                float val = (float)plane_h[yc*PHD + xc];
                acc += inb ? w * val : 0.0f;
            }
        }
        out[(a*PHD + b)*PHD + c] = acc;

        // advance linear index by 1024 = 5*192 + 64
        a += 5; b += 64;
        if (b >= PHD) { b -= PHD; a += 1; }
    }
}

// ---------------- launch -----------------------------------------------------
extern "C" void kernel_launch(void* const* d_in, const int* in_sizes, int n_in,
                              void* d_out, int out_size, void* d_ws, size_t ws_size,
                              hipStream_t stream)
{
    const float* Phantom = (const float*)d_in[0];   // 192^3
    const float* RI      = (const float*)d_in[1];   // (64^3, 2)
    const float* RayInit = (const float*)d_in[2];   // (4096, 5)
    float* out = (float*)d_out;

    float* meshXT = (float*)d_ws;                   // (64, 4096)
    float* meshYT = meshXT + NRAY2 * NSAMP;         // (64, 4096)

    Mats M;
    build_mats(M);

    ray_trace_kernel<<<NRAY2/8, 256, 0, stream>>>(RI, RayInit, meshXT, meshYT, M);
    sample_kernel<<<PHD, 1024, 0, stream>>>(Phantom, meshXT, meshYT, out);
}

// Round 4
// 156.298 us; speedup vs baseline: 2.0494x; 1.0480x over previous
//
#include <hip/hip_runtime.h>
#include <math.h>

#define NRAY2 4096
#define NSAMP 64
#define PHD 192
#define PLANE (PHD*PHD)          // 36864
constexpr float STEP = 1.0f / 63.0f;

struct Mats { float crd[16]; float drv[16]; };

// ---------------- host-side constant matrices (replicates numpy fp64 math) ---
static void mat_mul4(const double* A, const double* B, double* C) {
    for (int i = 0; i < 4; ++i)
        for (int j = 0; j < 4; ++j) {
            double s = 0.0;
            for (int k = 0; k < 4; ++k) s += A[i*4+k] * B[k*4+j];
            C[i*4+j] = s;
        }
}

static void build_mats(Mats& M) {
    const double tx = 0.1, ty = 0.05, tz = 0.02;
    const double cx = 0.5, cy = 0.5, cz = 0.5;
    auto ry = [](double t, double* m) {
        double c = cos(t), s = sin(t);
        double v[16] = {1,0,0,0, 0,c,-s,0, 0,s,c,0, 0,0,0,1};
        for (int i = 0; i < 16; ++i) m[i] = v[i];
    };
    auto rx = [](double t, double* m) {
        double c = cos(t), s = sin(t);
        double v[16] = {c,0,-s,0, 0,1,0,0, s,0,c,0, 0,0,0,1};
        for (int i = 0; i < 16; ++i) m[i] = v[i];
    };
    auto rz = [](double t, double* m) {
        double c = cos(t), s = sin(t);
        double v[16] = {c,-s,0,0, s,c,0,0, 0,0,1,0, 0,0,0,1};
        for (int i = 0; i < 16; ++i) m[i] = v[i];
    };
    double RY[16], RY_[16], RX[16], RX_[16], RZ[16], RZ_[16];
    ry(-ty, RY); ry(ty, RY_);
    rx(tx, RX);  rx(-tx, RX_);
    rz(-tz, RZ); rz(tz, RZ_);
    double S1[16] = {1,0,0,0, 0,1,0,0, 0,0,1,0, -cx,-cy,-cz,1};
    double S2[16] = {1,0,0,0, 0,1,0,0, 0,0,1,0,  cx, cy, cz,1};
    double t1[16], t2[16], t3[16], Mc[16], Md[16];
    mat_mul4(S1, RZ, t1);
    mat_mul4(t1, RY, t2);
    mat_mul4(t2, RX, t3);
    mat_mul4(t3, S2, Mc);
    mat_mul4(RX_, RY_, t1);
    mat_mul4(t1, RZ_, Md);
    for (int i = 0; i < 16; ++i) { M.crd[i] = (float)Mc[i]; M.drv[i] = (float)Md[i]; }
}

// 32-lane sum, all lanes get result: 4x DPP row_ror (VALU pipe) + 1 swizzle.
__device__ __forceinline__ float red32(float x) {
    int t;
    t = __builtin_amdgcn_update_dpp(0, __float_as_int(x), 0x121, 0xF, 0xF, true);
    x += __int_as_float(t);
    t = __builtin_amdgcn_update_dpp(0, __float_as_int(x), 0x122, 0xF, 0xF, true);
    x += __int_as_float(t);
    t = __builtin_amdgcn_update_dpp(0, __float_as_int(x), 0x124, 0xF, 0xF, true);
    x += __int_as_float(t);
    t = __builtin_amdgcn_update_dpp(0, __float_as_int(x), 0x128, 0xF, 0xF, true);
    x += __int_as_float(t);
    t = __builtin_amdgcn_ds_swizzle(__float_as_int(x), 0x401F);   // lane ^= 16
    x += __int_as_float(t);
    return x;
}

// ---------------- kernel 1: ray tracing -------------------------------------
__global__ __launch_bounds__(256) void ray_trace_kernel(
    const float* __restrict__ RI,       // (64^3, 2) interleaved [A, sig]
    const float* __restrict__ RayInit,  // (4096, 5)
    float* __restrict__ meshXT,         // (64, 4096)  stores 2X-1
    float* __restrict__ meshYT,         // (64, 4096)  stores 2Y-1
    Mats M)
{
    const int tid = threadIdx.x;
    const int nb  = tid & 31;
    const int ray = blockIdx.x * 8 + (tid >> 5);
    const bool act = nb < 27;

    float xr = 0.f, yr = 0.f, zr = 0.f;
    if (act) {
        int a0 = nb / 9, a1 = (nb / 3) % 3, a2 = nb % 3;
        xr = (float)(a1 - 1);
        yr = (float)(a0 - 1);
        zr = (float)(a2 - 1);
    }

    float X  = RayInit[ray*5 + 0];
    float dX = RayInit[ray*5 + 1];
    float Y  = RayInit[ray*5 + 2];
    float dY = RayInit[ray*5 + 3];
    float z  = RayInit[ray*5 + 4];

    if (nb == 0) meshXT[ray] = X*2.0f - 1.0f;
    if (nb == 1) meshYT[ray] = Y*2.0f - 1.0f;

    auto prep = [&](float pX, float pY, float pz,
                    float& ox, float& oy, float& oz,
                    float& oXn, float& oYn, float& oZn) -> const float2* {
        float x  = pY*M.crd[1] + pX*M.crd[5] + pz*M.crd[9]  + M.crd[13];
        float y  = pY*M.crd[0] + pX*M.crd[4] + pz*M.crd[8]  + M.crd[12];
        float zz = pY*M.crd[2] + pX*M.crd[6] + pz*M.crd[10] + M.crd[14];
        float XnL = __builtin_amdgcn_fmed3f(rintf(x *64.0f) + xr, 0.0f, 63.0f);
        float YnL = __builtin_amdgcn_fmed3f(rintf(y *64.0f) + yr, 0.0f, 63.0f);
        float ZnL = __builtin_amdgcn_fmed3f(rintf(zz*64.0f) + zr, 0.0f, 63.0f);
        // exact in fp32: values < 2^24
        int lin = (int)(YnL*4096.0f + XnL*64.0f + ZnL);
        ox = x; oy = y; oz = zz; oXn = XnL; oYn = YnL; oZn = ZnL;
        return (const float2*)RI + lin;
    };

    float cx_, cy_, cz_, Xn, Yn, Zn;
    float2 ri = *prep(X, Y, z, cx_, cy_, cz_, Xn, Yn, Zn);

    for (int s = 1; s < NSAMP; ++s) {
        // next eval position -> issue its gather NOW (one-step-ahead prefetch)
        float nX = X + dX*STEP, nY = Y + dY*STEP, nz = z + STEP;
        float ncx, ncy, ncz, nXn, nYn, nZn;
        float2 ri_n = *prep(nX, nY, nz, ncx, ncy, ncz, nXn, nYn, nZn);

        float dx = Xn*(1.0f/63.0f) - cx_;
        float dy = Yn*(1.0f/63.0f) - cy_;
        float dz = Zn*(1.0f/63.0f) - cz_;
        float inv_s2 = __builtin_amdgcn_rcpf(ri.y * ri.y);
        float e = __expf(-(dx*dx + dy*dy + dz*dz) * 0.5f * inv_s2) + 2e-7f;
        if (!act) e = 0.0f;
        float gdx = dx*inv_s2, gdy = dy*inv_s2, gdz = dz*inv_s2;
        float nu  = e * ri.x;

        float ni  = red32(e);
        float nuA = red32(nu);
        float sx  = red32(nu * gdx);
        float sy  = red32(nu * gdy);
        float sz  = red32(nu * gdz);
        float sdx = red32(e  * gdx);
        float sdy = red32(e  * gdy);
        float sdz = red32(e  * gdz);

        float r   = __builtin_amdgcn_rcpf(ni);
        float rn  = ni * __builtin_amdgcn_rcpf(nuA);   // 1/n = norm/nu_s
        float in2 = r * r;
        float gx_ = (ni*sx - nuA*sdx) * in2;
        float gy_ = (ni*sy - nuA*sdy) * in2;
        float gz_ = (ni*sz - nuA*sdz) * in2;

        float dndx = gy_*M.drv[1] + gx_*M.drv[5] + gz_*M.drv[9]  + M.drv[13];
        float dndy = gy_*M.drv[0] + gx_*M.drv[4] + gz_*M.drv[8]  + M.drv[12];
        float dndz = gy_*M.drv[2] + gx_*M.drv[6] + gz_*M.drv[10] + M.drv[14];

        float dX2 = (dndx - dndz*dX) * (1.0f + dX*dX) * rn;
        float dY2 = (dndy - dndz*dY) * (1.0f + dY*dY) * rn;

        X = nX; Y = nY; z = nz;
        dX += dX2 * STEP;
        dY += dY2 * STEP;

        if (nb == 0) meshXT[s*NRAY2 + ray] = X*2.0f - 1.0f;
        if (nb == 1) meshYT[s*NRAY2 + ray] = Y*2.0f - 1.0f;

        cx_ = ncx; cy_ = ncy; cz_ = ncz;
        Xn = nXn; Yn = nYn; Zn = nZn;
        ri = ri_n;
    }
}

// ---------------- kernel 2: fused resize + grid sample ----------------------
// One block per c-plane; phantom plane as fp16 in LDS; s-interpolated mesh
// slice in LDS. If `transposed` != 0, stores go CONTIGUOUS to
// outDst[c][a*192+b] (the scattered-store fix); else directly to out[a][b][c].
typedef _Float16 h16;
typedef _Float16 h16v4 __attribute__((ext_vector_type(4)));

__global__ __launch_bounds__(1024) void sample_kernel(
    const float* __restrict__ vol,      // 192^3
    const float* __restrict__ meshXT,   // (64, 4096)
    const float* __restrict__ meshYT,
    float* __restrict__ outDst,
    int transposed)
{
    __shared__ h16    plane_h[PLANE];     // 73,728 B
    __shared__ float2 slice[64*64];       // 32,768 B
    __shared__ float  wTab[PHD];
    __shared__ int    iTab[PHD];

    const int tid = threadIdx.x;
    const int blk = blockIdx.x;
    // consecutive c on the same XCD (L2 locality for slice reads / line merge)
    const int c = (blk >> 3) + 24 * (blk & 7);

    if (tid < PHD) {
        float p = tid * (63.0f / 191.0f);
        int i0 = min((int)p, 62);
        iTab[tid] = i0;
        wTab[tid] = p - (float)i0;
    }

    {
        const float4* src = (const float4*)(vol + c * PLANE);
        h16v4* dst = (h16v4*)plane_h;
        #pragma unroll
        for (int k = 0; k < (PLANE/4)/1024; ++k) {
            float4 v = src[tid + k*1024];
            h16v4 hv = {(h16)v.x, (h16)v.y, (h16)v.z, (h16)v.w};
            dst[tid + k*1024] = hv;
        }
    }

    float ps = c * (63.0f / 191.0f);
    int s0 = min((int)ps, 62);
    float wc = ps - (float)s0, wc0 = 1.0f - wc;
    {
        const float* x0 = meshXT + s0*NRAY2;
        const float* x1 = meshXT + (s0+1)*NRAY2;
        const float* y0 = meshYT + s0*NRAY2;
        const float* y1 = meshYT + (s0+1)*NRAY2;
        #pragma unroll
        for (int k = 0; k < 4096/1024; ++k) {
            int t = tid + k*1024;
            slice[t] = make_float2(x0[t]*wc0 + x1[t]*wc,
                                   y0[t]*wc0 + y1[t]*wc);
        }
    }
    __syncthreads();

    int a = tid / PHD, b = tid % PHD;
    #pragma unroll 2
    for (int k = 0; k < PLANE/1024; ++k) {
        int i0 = iTab[a]; float wa = wTab[a];
        int j0 = iTab[b]; float wb = wTab[b];

        float2 s00 = slice[i0*64 + j0];
        float2 s01 = slice[i0*64 + j0 + 1];
        float2 s10 = slice[(i0+1)*64 + j0];
        float2 s11 = slice[(i0+1)*64 + j0 + 1];

        float wb0 = 1.0f - wb, wa0 = 1.0f - wa;
        float gx = (s00.x*wb0 + s01.x*wb)*wa0 + (s10.x*wb0 + s11.x*wb)*wa;
        float gy = (s00.y*wb0 + s01.y*wb)*wa0 + (s10.y*wb0 + s11.y*wb)*wa;

        float ix = (gx + 1.0f) * 0.5f * 191.0f;
        float iy = (gy + 1.0f) * 0.5f * 191.0f;
        float x0f = floorf(ix); float fx = ix - x0f;
        float y0f = floorf(iy); float fy = iy - y0f;

        float acc = 0.0f;
        #pragma unroll
        for (int dyy = 0; dyy < 2; ++dyy) {
            #pragma unroll
            for (int dxx = 0; dxx < 2; ++dxx) {
                float xi = x0f + (float)dxx;
                float yi = y0f + (float)dyy;
                bool inb = (xi >= 0.0f) && (xi <= 191.0f) &&
                           (yi >= 0.0f) && (yi <= 191.0f);
                int xc = min(max((int)xi, 0), PHD - 1);
                int yc = min(max((int)yi, 0), PHD - 1);
                float w = (dxx ? fx : 1.0f - fx) * (dyy ? fy : 1.0f - fy);
                float val = (float)plane_h[yc*PHD + xc];
                acc += inb ? w * val : 0.0f;
            }
        }

        if (transposed) {
            // contiguous: lane-consecutive addresses (tid + k*1024)
            outDst[c*PLANE + tid + k*1024] = acc;
        } else {
            outDst[(a*PHD + b)*PHD + c] = acc;
        }

        a += 5; b += 64;
        if (b >= PHD) { b -= PHD; a += 1; }
    }
}

// ---------------- kernel 3: (b,c) tile transpose ----------------------------
// out[a][b][c] = outT[c][a*192 + b]; 32x32 LDS tiles, coalesced both ways.
__global__ __launch_bounds__(256) void transpose_kernel(
    const float* __restrict__ outT, float* __restrict__ out)
{
    __shared__ float t[32][33];
    const int a  = blockIdx.z;
    const int b0 = blockIdx.x * 32;
    const int c0 = blockIdx.y * 32;
    const int tx = threadIdx.x, ty = threadIdx.y;   // 32 x 8

    const float* src = outT + (size_t)(c0 + ty) * PLANE + a*PHD + b0 + tx;
    #pragma unroll
    for (int j = 0; j < 4; ++j)
        t[ty + 8*j][tx] = src[(size_t)(8*j) * PLANE];
    __syncthreads();

    float* dst = out + (size_t)a * PLANE + (size_t)(b0 + ty) * PHD + c0 + tx;
    #pragma unroll
    for (int j = 0; j < 4; ++j)
        dst[(size_t)(8*j) * PHD] = t[tx][ty + 8*j];
}

// ---------------- launch -----------------------------------------------------
extern "C" void kernel_launch(void* const* d_in, const int* in_sizes, int n_in,
                              void* d_out, int out_size, void* d_ws, size_t ws_size,
                              hipStream_t stream)
{
    const float* Phantom = (const float*)d_in[0];   // 192^3
    const float* RI      = (const float*)d_in[1];   // (64^3, 2)
    const float* RayInit = (const float*)d_in[2];   // (4096, 5)
    float* out = (float*)d_out;

    float* meshXT = (float*)d_ws;                   // (64, 4096)   1 MB
    float* meshYT = meshXT + NRAY2 * NSAMP;         // (64, 4096)   1 MB
    float* outT   = meshYT + NRAY2 * NSAMP;         // 192^3        28.3 MB

    const size_t need = (size_t)(2 * NRAY2 * NSAMP + PHD*PLANE) * sizeof(float);
    const int use_transpose = (ws_size >= need) ? 1 : 0;

    Mats M;
    build_mats(M);

    ray_trace_kernel<<<NRAY2/8, 256, 0, stream>>>(RI, RayInit, meshXT, meshYT, M);

    if (use_transpose) {
        sample_kernel<<<PHD, 1024, 0, stream>>>(Phantom, meshXT, meshYT, outT, 1);
        transpose_kernel<<<dim3(6, 6, PHD), dim3(32, 8), 0, stream>>>(outT, out);
    } else {
        sample_kernel<<<PHD, 1024, 0, stream>>>(Phantom, meshXT, meshYT, out, 0);
    }
}